// Round 1
// baseline (268.930 us; speedup 1.0000x reference)
//
#include <hip/hip_runtime.h>
#include <math.h>

typedef unsigned short u16;
typedef __bf16 bf16x8 __attribute__((ext_vector_type(8)));
typedef float f32x4 __attribute__((ext_vector_type(4)));
typedef u16 u16x4 __attribute__((ext_vector_type(4)));
typedef u16 u16x8 __attribute__((ext_vector_type(8)));

#define DEV __device__ __forceinline__

// fp32 -> bf16 RNE (inputs are never NaN here)
DEV u16 f2bf(float f) {
  unsigned u = __builtin_bit_cast(unsigned, f);
  u += 0x7FFFu + ((u >> 16) & 1u);
  return (u16)(u >> 16);
}

// async global->LDS, 16B per lane; LDS dest is wave-uniform base + lane*16
DEV void gload16(const void* g, void* l) {
  __builtin_amdgcn_global_load_lds((__attribute__((address_space(1))) void*)g,
                                   (__attribute__((address_space(3))) void*)l, 16, 0, 0);
}

// ---------------- fp32 -> bf16 convert (weights) ----------------
__launch_bounds__(256)
__global__ void cvt_f32_bf16(const float* __restrict__ in, u16* __restrict__ out, int n4) {
  int i = blockIdx.x * 256 + threadIdx.x;
  if (i < n4) {
    float4 v = ((const float4*)in)[i];
    u16x4 o = { f2bf(v.x), f2bf(v.y), f2bf(v.z), f2bf(v.w) };
    ((u16x4*)out)[i] = o;
  }
}

// ---------------- LayerNorm over D=1024, one block per row ----------------
__launch_bounds__(256)
__global__ void ln_rows(const float* __restrict__ x, const float* __restrict__ gam,
                        const float* __restrict__ bet, u16* __restrict__ out) {
  int row = blockIdx.x;
  int t = threadIdx.x;
  float4 v = ((const float4*)(x + (size_t)row * 1024))[t];
  float s = v.x + v.y + v.z + v.w;
  float s2 = v.x * v.x + v.y * v.y + v.z * v.z + v.w * v.w;
  for (int off = 1; off < 64; off <<= 1) {
    s += __shfl_xor(s, off);
    s2 += __shfl_xor(s2, off);
  }
  __shared__ float red[8];
  int wv = t >> 6, ln = t & 63;
  if (ln == 0) { red[wv] = s; red[wv + 4] = s2; }
  __syncthreads();
  s = red[0] + red[1] + red[2] + red[3];
  s2 = red[4] + red[5] + red[6] + red[7];
  float mu = s * (1.f / 1024.f);
  float var = s2 * (1.f / 1024.f) - mu * mu;
  float rs = rsqrtf(var + 1e-5f);
  float4 gv = ((const float4*)gam)[t];
  float4 bv = ((const float4*)bet)[t];
  u16x4 o = { f2bf((v.x - mu) * rs * gv.x + bv.x), f2bf((v.y - mu) * rs * gv.y + bv.y),
              f2bf((v.z - mu) * rs * gv.z + bv.z), f2bf((v.w - mu) * rs * gv.w + bv.w) };
  ((u16x4*)(out + (size_t)row * 1024))[t] = o;
}

// ---------------- generic bf16 GEMM: C[M,N] = A[M,K] @ B[N,K]^T ----------------
// EPI: 0 = store bf16; 1 = +bias, exact GELU, store bf16; 2 = +bias +resid, store f32;
//      3 = +resid, store f32
template <int BM, int BN, int WR, int WC, int EPI>
__launch_bounds__(256, 2)
__global__ void gemm_bt(const u16* __restrict__ A, const u16* __restrict__ B,
                        void* __restrict__ C, const float* __restrict__ bias,
                        const float* __restrict__ resid, int M, int N, int K) {
  constexpr int FM = BM / WR / 16;
  constexpr int FN = BN / WC / 16;
  __shared__ u16 As[BM * 32];
  __shared__ u16 Bs[BN * 32];
  const int t = threadIdx.x, lane = t & 63, w = t >> 6;
  const int wr = w / WC, wc = w % WC;
  const int g = lane >> 4, l16 = lane & 15;
  const int m0 = blockIdx.y * BM, n0 = blockIdx.x * BN;
  f32x4 acc[FM][FN] = {};
  const int nkt = K >> 5;
  for (int kt = 0; kt < nkt; ++kt) {
    const u16* Ag = A + (size_t)m0 * K + kt * 32;
    const u16* Bg = B + (size_t)n0 * K + kt * 32;
#pragma unroll
    for (int i = 0; i < BM / 64; ++i) {
      int c = i * 256 + t;
      gload16(Ag + (size_t)(c >> 2) * K + (c & 3) * 8, &As[(i * 256 + w * 64) * 8]);
    }
#pragma unroll
    for (int i = 0; i < BN / 64; ++i) {
      int c = i * 256 + t;
      gload16(Bg + (size_t)(c >> 2) * K + (c & 3) * 8, &Bs[(i * 256 + w * 64) * 8]);
    }
    __syncthreads();
    bf16x8 af[FM], bfr[FN];
#pragma unroll
    for (int m = 0; m < FM; ++m)
      af[m] = *(const bf16x8*)&As[(wr * FM * 16 + m * 16 + l16) * 32 + g * 8];
#pragma unroll
    for (int n = 0; n < FN; ++n)
      bfr[n] = *(const bf16x8*)&Bs[(wc * FN * 16 + n * 16 + l16) * 32 + g * 8];
#pragma unroll
    for (int m = 0; m < FM; ++m)
#pragma unroll
      for (int n = 0; n < FN; ++n)
        acc[m][n] = __builtin_amdgcn_mfma_f32_16x16x32_bf16(af[m], bfr[n], acc[m][n], 0, 0, 0);
    __syncthreads();
  }
#pragma unroll
  for (int m = 0; m < FM; ++m)
#pragma unroll
    for (int n = 0; n < FN; ++n)
#pragma unroll
      for (int r = 0; r < 4; ++r) {
        int row = m0 + wr * FM * 16 + m * 16 + g * 4 + r;
        int col = n0 + wc * FN * 16 + n * 16 + l16;
        size_t idx = (size_t)row * N + col;
        float v = acc[m][n][r];
        if constexpr (EPI == 0) {
          ((u16*)C)[idx] = f2bf(v);
        } else if constexpr (EPI == 1) {
          v += bias[col];
          v = 0.5f * v * (1.f + erff(v * 0.70710678118f));
          ((u16*)C)[idx] = f2bf(v);
        } else if constexpr (EPI == 2) {
          ((float*)C)[idx] = v + bias[col] + resid[idx];
        } else {
          ((float*)C)[idx] = v + resid[idx];
        }
      }
}

// ---------------- fused QKV projection (one launch, 384 blocks) ----------------
__launch_bounds__(256, 2)
__global__ void gemm_qkv(const u16* __restrict__ A, const u16* __restrict__ B0,
                         const u16* __restrict__ B1, const u16* __restrict__ B2,
                         u16* __restrict__ C0, u16* __restrict__ C1, u16* __restrict__ C2) {
  constexpr int BM = 128, BN = 128, FM = 4, FN = 4;
  const int K = 1024, N = 1024;
  const int which = blockIdx.x >> 3;
  const u16* B = which == 0 ? B0 : which == 1 ? B1 : B2;
  u16* C = which == 0 ? C0 : which == 1 ? C1 : C2;
  __shared__ u16 As[BM * 32];
  __shared__ u16 Bs[BN * 32];
  const int t = threadIdx.x, lane = t & 63, w = t >> 6;
  const int wr = w >> 1, wc = w & 1;
  const int g = lane >> 4, l16 = lane & 15;
  const int m0 = blockIdx.y * BM, n0 = (blockIdx.x & 7) * BN;
  f32x4 acc[FM][FN] = {};
  for (int kt = 0; kt < 32; ++kt) {
    const u16* Ag = A + (size_t)m0 * K + kt * 32;
    const u16* Bg = B + (size_t)n0 * K + kt * 32;
#pragma unroll
    for (int i = 0; i < 2; ++i) {
      int c = i * 256 + t;
      gload16(Ag + (size_t)(c >> 2) * K + (c & 3) * 8, &As[(i * 256 + w * 64) * 8]);
    }
#pragma unroll
    for (int i = 0; i < 2; ++i) {
      int c = i * 256 + t;
      gload16(Bg + (size_t)(c >> 2) * K + (c & 3) * 8, &Bs[(i * 256 + w * 64) * 8]);
    }
    __syncthreads();
    bf16x8 af[FM], bfr[FN];
#pragma unroll
    for (int m = 0; m < FM; ++m)
      af[m] = *(const bf16x8*)&As[(wr * 64 + m * 16 + l16) * 32 + g * 8];
#pragma unroll
    for (int n = 0; n < FN; ++n)
      bfr[n] = *(const bf16x8*)&Bs[(wc * 64 + n * 16 + l16) * 32 + g * 8];
#pragma unroll
    for (int m = 0; m < FM; ++m)
#pragma unroll
      for (int n = 0; n < FN; ++n)
        acc[m][n] = __builtin_amdgcn_mfma_f32_16x16x32_bf16(af[m], bfr[n], acc[m][n], 0, 0, 0);
    __syncthreads();
  }
#pragma unroll
  for (int m = 0; m < FM; ++m)
#pragma unroll
    for (int n = 0; n < FN; ++n)
#pragma unroll
      for (int r = 0; r < 4; ++r) {
        int row = m0 + wr * 64 + m * 16 + g * 4 + r;
        int col = n0 + wc * 64 + n * 16 + l16;
        C[(size_t)row * N + col] = f2bf(acc[m][n][r]);
      }
}

// ---------------- flash attention, causal + ALiBi ----------------
// grid: (32 q-blocks of 64, 16 heads); 4 waves, each owns 16 query rows.
// K and V fragments read straight from global (per-head K/V = 256KB, L2-resident).
__launch_bounds__(256, 2)
__global__ void attn_fwd(const u16* __restrict__ Q, const u16* __restrict__ Kb,
                         const u16* __restrict__ Vb, const float* __restrict__ slopes,
                         u16* __restrict__ O) {
  const int qb = blockIdx.x;
  const int h = blockIdx.y;
  const int t = threadIdx.x, lane = t & 63, w = t >> 6;
  const int g = lane >> 4, l16 = lane & 15;
  const float slope = slopes[h];
  const int q0 = qb * 64 + w * 16;

  bf16x8 qf[2];
#pragma unroll
  for (int kk = 0; kk < 2; ++kk)
    qf[kk] = *(const bf16x8*)&Q[(size_t)(q0 + l16) * 1024 + h * 64 + kk * 32 + g * 8];

  f32x4 o_acc[4] = {};
  float m_run[4], l_run[4];
#pragma unroll
  for (int r = 0; r < 4; ++r) { m_run[r] = -1e30f; l_run[r] = 0.f; }

  __shared__ u16 Ps[4][16][72];  // per-wave P tile, padded stride

  for (int j = 0; j <= qb; ++j) {
    const int kv0 = j * 64;
    // ---- S = Q K^T (16 q-rows x 64 keys per wave) ----
    f32x4 s[4];
#pragma unroll
    for (int n = 0; n < 4; ++n) {
      bf16x8 kf0 = *(const bf16x8*)&Kb[(size_t)(kv0 + n * 16 + l16) * 1024 + h * 64 + g * 8];
      bf16x8 kf1 = *(const bf16x8*)&Kb[(size_t)(kv0 + n * 16 + l16) * 1024 + h * 64 + 32 + g * 8];
      f32x4 z = {};
      s[n] = __builtin_amdgcn_mfma_f32_16x16x32_bf16(qf[0], kf0, z, 0, 0, 0);
      s[n] = __builtin_amdgcn_mfma_f32_16x16x32_bf16(qf[1], kf1, s[n], 0, 0, 0);
    }
    // ---- scale + ALiBi + causal mask ----
    float sv[4][4];
    float mtile[4] = { -1e30f, -1e30f, -1e30f, -1e30f };
#pragma unroll
    for (int n = 0; n < 4; ++n) {
      int kj = kv0 + n * 16 + l16;
#pragma unroll
      for (int r = 0; r < 4; ++r) {
        int qi = q0 + g * 4 + r;
        float val = s[n][r] * 0.125f - slope * (float)(kj - qi);
        val = (kj <= qi) ? val : -1e30f;
        sv[n][r] = val;
        mtile[r] = fmaxf(mtile[r], val);
      }
    }
    // ---- online softmax: row stats across the 16-lane group ----
#pragma unroll
    for (int r = 0; r < 4; ++r) {
      float v = mtile[r];
      v = fmaxf(v, __shfl_xor(v, 1));
      v = fmaxf(v, __shfl_xor(v, 2));
      v = fmaxf(v, __shfl_xor(v, 4));
      v = fmaxf(v, __shfl_xor(v, 8));
      mtile[r] = v;
    }
    float sc[4];
#pragma unroll
    for (int r = 0; r < 4; ++r) {
      float mnew = fmaxf(m_run[r], mtile[r]);
      sc[r] = __expf(m_run[r] - mnew);
      m_run[r] = mnew;
    }
    float tsum[4] = { 0.f, 0.f, 0.f, 0.f };
#pragma unroll
    for (int n = 0; n < 4; ++n)
#pragma unroll
      for (int r = 0; r < 4; ++r) {
        float p = __expf(sv[n][r] - m_run[r]);
        sv[n][r] = p;
        tsum[r] += p;
      }
#pragma unroll
    for (int r = 0; r < 4; ++r) {
      float v = tsum[r];
      v += __shfl_xor(v, 1);
      v += __shfl_xor(v, 2);
      v += __shfl_xor(v, 4);
      v += __shfl_xor(v, 8);
      l_run[r] = l_run[r] * sc[r] + v;
    }
#pragma unroll
    for (int d = 0; d < 4; ++d)
#pragma unroll
      for (int r = 0; r < 4; ++r) o_acc[d][r] *= sc[r];
    // ---- P -> LDS (layout fix for MFMA A-fragment), then O += P V ----
#pragma unroll
    for (int n = 0; n < 4; ++n)
#pragma unroll
      for (int r = 0; r < 4; ++r)
        Ps[w][g * 4 + r][n * 16 + l16] = f2bf(sv[n][r]);
    bf16x8 pf[2];
#pragma unroll
    for (int kk = 0; kk < 2; ++kk)
      pf[kk] = *(const bf16x8*)&Ps[w][l16][kk * 32 + g * 8];
#pragma unroll
    for (int d = 0; d < 4; ++d) {
#pragma unroll
      for (int kk = 0; kk < 2; ++kk) {
        u16x8 vv;
#pragma unroll
        for (int jj = 0; jj < 8; ++jj)
          vv[jj] = Vb[(size_t)(kv0 + kk * 32 + g * 8 + jj) * 1024 + h * 64 + d * 16 + l16];
        o_acc[d] = __builtin_amdgcn_mfma_f32_16x16x32_bf16(pf[kk], __builtin_bit_cast(bf16x8, vv),
                                                           o_acc[d], 0, 0, 0);
      }
    }
  }
  // ---- normalize + store ----
#pragma unroll
  for (int d = 0; d < 4; ++d)
#pragma unroll
    for (int r = 0; r < 4; ++r) {
      int row = q0 + g * 4 + r;
      O[(size_t)row * 1024 + h * 64 + d * 16 + l16] = f2bf(o_acc[d][r] / l_run[r]);
    }
}

// ---------------- launcher ----------------
extern "C" void kernel_launch(void* const* d_in, const int* in_sizes, int n_in,
                              void* d_out, int out_size, void* d_ws, size_t ws_size,
                              hipStream_t stream) {
  const float* x = (const float*)d_in[0];
  const float* slopes = (const float*)d_in[1];
  const float* wq = (const float*)d_in[2];
  const float* wk = (const float*)d_in[3];
  const float* wv = (const float*)d_in[4];
  const float* wo = (const float*)d_in[5];
  const float* ff1w = (const float*)d_in[6];
  const float* ff1b = (const float*)d_in[7];
  const float* ff2w = (const float*)d_in[8];
  const float* ff2b = (const float*)d_in[9];
  const float* ln1g = (const float*)d_in[10];
  const float* ln1b = (const float*)d_in[11];
  const float* ln2g = (const float*)d_in[12];
  const float* ln2b = (const float*)d_in[13];
  float* out = (float*)d_out;

  if (ws_size < (size_t)(56u << 20)) return;  // need 56MB scratch

  char* ws = (char*)d_ws;
  u16* hbuf = (u16*)(ws + 0);            // 4MB: h (LN1 out), later reused as attn output
  u16* Qb = (u16*)(ws + (4u << 20));     // 4MB
  u16* Kbf = (u16*)(ws + (8u << 20));    // 4MB
  u16* Vbf = (u16*)(ws + (12u << 20));   // 4MB
  u16* ffact = Qb;                       // 16MB span (Q/K/V dead after attention)
  float* x2 = (float*)(ws + (20u << 20)); // 8MB
  u16* h2 = (u16*)(ws + (28u << 20));    // 4MB
  u16* wqb = (u16*)(ws + (32u << 20));
  u16* wkb = (u16*)(ws + (34u << 20));
  u16* wvb = (u16*)(ws + (36u << 20));
  u16* wob = (u16*)(ws + (38u << 20));
  u16* ff1wb = (u16*)(ws + (40u << 20)); // 8MB
  u16* ff2wb = (u16*)(ws + (48u << 20)); // 8MB
  u16* attnO = hbuf;

  auto cvt = [&](const float* src, u16* dst, int n) {
    int n4 = n >> 2;
    cvt_f32_bf16<<<(n4 + 255) / 256, 256, 0, stream>>>(src, dst, n4);
  };
  cvt(wq, wqb, 1 << 20);
  cvt(wk, wkb, 1 << 20);
  cvt(wv, wvb, 1 << 20);
  cvt(wo, wob, 1 << 20);
  cvt(ff1w, ff1wb, 1 << 22);
  cvt(ff2w, ff2wb, 1 << 22);

  ln_rows<<<2048, 256, 0, stream>>>(x, ln1g, ln1b, hbuf);
  gemm_qkv<<<dim3(24, 16), 256, 0, stream>>>(hbuf, wqb, wkb, wvb, Qb, Kbf, Vbf);
  attn_fwd<<<dim3(32, 16), 256, 0, stream>>>(Qb, Kbf, Vbf, slopes, attnO);
  // x2 = x + attnO @ wo^T
  gemm_bt<64, 128, 1, 4, 3><<<dim3(8, 32), 256, 0, stream>>>(
      attnO, wob, x2, nullptr, x, 2048, 1024, 1024);
  ln_rows<<<2048, 256, 0, stream>>>(x2, ln2g, ln2b, h2);
  // ffact = gelu(h2 @ ff1^T + b1)
  gemm_bt<128, 128, 2, 2, 1><<<dim3(32, 16), 256, 0, stream>>>(
      h2, ff1wb, ffact, ff1b, nullptr, 2048, 4096, 1024);
  // out = x2 + ffact @ ff2^T + b2
  gemm_bt<64, 128, 1, 4, 2><<<dim3(8, 32), 256, 0, stream>>>(
      ffact, ff2wb, out, ff2b, x2, 2048, 1024, 4096);
}

// Round 2
// 241.227 us; speedup vs baseline: 1.1148x; 1.1148x over previous
//
#include <hip/hip_runtime.h>
#include <math.h>

typedef unsigned short u16;
typedef __bf16 bf16x8 __attribute__((ext_vector_type(8)));
typedef float f32x4 __attribute__((ext_vector_type(4)));
typedef u16 u16x4 __attribute__((ext_vector_type(4)));
typedef u16 u16x8 __attribute__((ext_vector_type(8)));

#define DEV __device__ __forceinline__

// fp32 -> bf16 RNE (inputs are never NaN here)
DEV u16 f2bf(float f) {
  unsigned u = __builtin_bit_cast(unsigned, f);
  u += 0x7FFFu + ((u >> 16) & 1u);
  return (u16)(u >> 16);
}

// async global->LDS, 16B per lane; LDS dest is wave-uniform base + lane*16
DEV void gload16(const void* g, void* l) {
  __builtin_amdgcn_global_load_lds((__attribute__((address_space(1))) void*)g,
                                   (__attribute__((address_space(3))) void*)l, 16, 0, 0);
}

// ---------------- fp32 -> bf16 convert (weights) ----------------
__launch_bounds__(256)
__global__ void cvt_f32_bf16(const float* __restrict__ in, u16* __restrict__ out, int n4) {
  int i = blockIdx.x * 256 + threadIdx.x;
  if (i < n4) {
    float4 v = ((const float4*)in)[i];
    u16x4 o = { f2bf(v.x), f2bf(v.y), f2bf(v.z), f2bf(v.w) };
    ((u16x4*)out)[i] = o;
  }
}

// ---------------- LayerNorm over D=1024, one block per row ----------------
__launch_bounds__(256)
__global__ void ln_rows(const float* __restrict__ x, const float* __restrict__ gam,
                        const float* __restrict__ bet, u16* __restrict__ out) {
  int row = blockIdx.x;
  int t = threadIdx.x;
  float4 v = ((const float4*)(x + (size_t)row * 1024))[t];
  float s = v.x + v.y + v.z + v.w;
  float s2 = v.x * v.x + v.y * v.y + v.z * v.z + v.w * v.w;
  for (int off = 1; off < 64; off <<= 1) {
    s += __shfl_xor(s, off);
    s2 += __shfl_xor(s2, off);
  }
  __shared__ float red[8];
  int wv = t >> 6, ln = t & 63;
  if (ln == 0) { red[wv] = s; red[wv + 4] = s2; }
  __syncthreads();
  s = red[0] + red[1] + red[2] + red[3];
  s2 = red[4] + red[5] + red[6] + red[7];
  float mu = s * (1.f / 1024.f);
  float var = s2 * (1.f / 1024.f) - mu * mu;
  float rs = rsqrtf(var + 1e-5f);
  float4 gv = ((const float4*)gam)[t];
  float4 bv = ((const float4*)bet)[t];
  u16x4 o = { f2bf((v.x - mu) * rs * gv.x + bv.x), f2bf((v.y - mu) * rs * gv.y + bv.y),
              f2bf((v.z - mu) * rs * gv.z + bv.z), f2bf((v.w - mu) * rs * gv.w + bv.w) };
  ((u16x4*)(out + (size_t)row * 1024))[t] = o;
}

// ---------------- V transpose: Vt[h][d][s] = V[s][h*64+d] ----------------
// grid (32 s-tiles, 16 heads), 256 threads; LDS tile 64x64
__launch_bounds__(256)
__global__ void transpose_v(const u16* __restrict__ V, u16* __restrict__ Vt) {
  const int st = blockIdx.x, h = blockIdx.y;
  __shared__ u16 tile[64][72];  // row stride 144B (multiple of 16)
  const int t = threadIdx.x;
  const int r = t >> 3, c8 = t & 7;
#pragma unroll
  for (int i = 0; i < 2; ++i) {
    int row = i * 32 + r;
    *(u16x8*)&tile[row][c8 * 8] =
        *(const u16x8*)&V[(size_t)(st * 64 + row) * 1024 + h * 64 + c8 * 8];
  }
  __syncthreads();
#pragma unroll
  for (int i = 0; i < 2; ++i) {
    int d = i * 32 + r;
    u16x8 o;
#pragma unroll
    for (int jj = 0; jj < 8; ++jj) o[jj] = tile[c8 * 8 + jj][d];
    *(u16x8*)&Vt[(size_t)(h * 64 + d) * 2048 + st * 64 + c8 * 8] = o;
  }
}

// ---------------- generic bf16 GEMM: C[M,N] = A[M,K] @ B[N,K]^T ----------------
// EPI: 0 = store bf16; 1 = +bias, exact GELU, store bf16; 2 = +bias +resid, store f32;
//      3 = +resid, store f32
template <int BM, int BN, int WR, int WC, int EPI>
__launch_bounds__(256, 2)
__global__ void gemm_bt(const u16* __restrict__ A, const u16* __restrict__ B,
                        void* __restrict__ C, const float* __restrict__ bias,
                        const float* __restrict__ resid, int M, int N, int K) {
  constexpr int FM = BM / WR / 16;
  constexpr int FN = BN / WC / 16;
  __shared__ u16 As[BM * 32];
  __shared__ u16 Bs[BN * 32];
  const int t = threadIdx.x, lane = t & 63, w = t >> 6;
  const int wr = w / WC, wc = w % WC;
  const int g = lane >> 4, l16 = lane & 15;
  const int m0 = blockIdx.y * BM, n0 = blockIdx.x * BN;
  f32x4 acc[FM][FN] = {};
  const int nkt = K >> 5;
  for (int kt = 0; kt < nkt; ++kt) {
    const u16* Ag = A + (size_t)m0 * K + kt * 32;
    const u16* Bg = B + (size_t)n0 * K + kt * 32;
#pragma unroll
    for (int i = 0; i < BM / 64; ++i) {
      int c = i * 256 + t;
      gload16(Ag + (size_t)(c >> 2) * K + (c & 3) * 8, &As[(i * 256 + w * 64) * 8]);
    }
#pragma unroll
    for (int i = 0; i < BN / 64; ++i) {
      int c = i * 256 + t;
      gload16(Bg + (size_t)(c >> 2) * K + (c & 3) * 8, &Bs[(i * 256 + w * 64) * 8]);
    }
    __syncthreads();
    bf16x8 af[FM], bfr[FN];
#pragma unroll
    for (int m = 0; m < FM; ++m)
      af[m] = *(const bf16x8*)&As[(wr * FM * 16 + m * 16 + l16) * 32 + g * 8];
#pragma unroll
    for (int n = 0; n < FN; ++n)
      bfr[n] = *(const bf16x8*)&Bs[(wc * FN * 16 + n * 16 + l16) * 32 + g * 8];
#pragma unroll
    for (int m = 0; m < FM; ++m)
#pragma unroll
      for (int n = 0; n < FN; ++n)
        acc[m][n] = __builtin_amdgcn_mfma_f32_16x16x32_bf16(af[m], bfr[n], acc[m][n], 0, 0, 0);
    __syncthreads();
  }
#pragma unroll
  for (int m = 0; m < FM; ++m)
#pragma unroll
    for (int n = 0; n < FN; ++n)
#pragma unroll
      for (int r = 0; r < 4; ++r) {
        int row = m0 + wr * FM * 16 + m * 16 + g * 4 + r;
        int col = n0 + wc * FN * 16 + n * 16 + l16;
        size_t idx = (size_t)row * N + col;
        float v = acc[m][n][r];
        if constexpr (EPI == 0) {
          ((u16*)C)[idx] = f2bf(v);
        } else if constexpr (EPI == 1) {
          v += bias[col];
          v = 0.5f * v * (1.f + erff(v * 0.70710678118f));
          ((u16*)C)[idx] = f2bf(v);
        } else if constexpr (EPI == 2) {
          ((float*)C)[idx] = v + bias[col] + resid[idx];
        } else {
          ((float*)C)[idx] = v + resid[idx];
        }
      }
}

// ---------------- fused QKV projection (one launch, 384 blocks) ----------------
__launch_bounds__(256, 2)
__global__ void gemm_qkv(const u16* __restrict__ A, const u16* __restrict__ B0,
                         const u16* __restrict__ B1, const u16* __restrict__ B2,
                         u16* __restrict__ C0, u16* __restrict__ C1, u16* __restrict__ C2) {
  constexpr int BM = 128, BN = 128, FM = 4, FN = 4;
  const int K = 1024, N = 1024;
  const int which = blockIdx.x >> 3;
  const u16* B = which == 0 ? B0 : which == 1 ? B1 : B2;
  u16* C = which == 0 ? C0 : which == 1 ? C1 : C2;
  __shared__ u16 As[BM * 32];
  __shared__ u16 Bs[BN * 32];
  const int t = threadIdx.x, lane = t & 63, w = t >> 6;
  const int wr = w >> 1, wc = w & 1;
  const int g = lane >> 4, l16 = lane & 15;
  const int m0 = blockIdx.y * BM, n0 = (blockIdx.x & 7) * BN;
  f32x4 acc[FM][FN] = {};
  for (int kt = 0; kt < 32; ++kt) {
    const u16* Ag = A + (size_t)m0 * K + kt * 32;
    const u16* Bg = B + (size_t)n0 * K + kt * 32;
#pragma unroll
    for (int i = 0; i < 2; ++i) {
      int c = i * 256 + t;
      gload16(Ag + (size_t)(c >> 2) * K + (c & 3) * 8, &As[(i * 256 + w * 64) * 8]);
    }
#pragma unroll
    for (int i = 0; i < 2; ++i) {
      int c = i * 256 + t;
      gload16(Bg + (size_t)(c >> 2) * K + (c & 3) * 8, &Bs[(i * 256 + w * 64) * 8]);
    }
    __syncthreads();
    bf16x8 af[FM], bfr[FN];
#pragma unroll
    for (int m = 0; m < FM; ++m)
      af[m] = *(const bf16x8*)&As[(wr * 64 + m * 16 + l16) * 32 + g * 8];
#pragma unroll
    for (int n = 0; n < FN; ++n)
      bfr[n] = *(const bf16x8*)&Bs[(wc * 64 + n * 16 + l16) * 32 + g * 8];
#pragma unroll
    for (int m = 0; m < FM; ++m)
#pragma unroll
      for (int n = 0; n < FN; ++n)
        acc[m][n] = __builtin_amdgcn_mfma_f32_16x16x32_bf16(af[m], bfr[n], acc[m][n], 0, 0, 0);
    __syncthreads();
  }
#pragma unroll
  for (int m = 0; m < FM; ++m)
#pragma unroll
    for (int n = 0; n < FN; ++n)
#pragma unroll
      for (int r = 0; r < 4; ++r) {
        int row = m0 + wr * 64 + m * 16 + g * 4 + r;
        int col = n0 + wc * 64 + n * 16 + l16;
        C[(size_t)row * N + col] = f2bf(acc[m][n][r]);
      }
}

// ---------------- flash attention, causal + ALiBi ----------------
// grid: (16 pair-blocks, 16 heads); 4 waves, each owns 16 query rows of a
// 64-row q-block. Block processes paired q-blocks (bx, 31-bx): constant 33
// j-tiles per block -> balanced causal work. K and Vt fragments read straight
// from global (per-head 256KB each, L2-resident). Vt is pre-transposed so PV
// B-fragments are contiguous 16B loads.
__launch_bounds__(256, 2)
__global__ void attn_fwd(const u16* __restrict__ Q, const u16* __restrict__ Kb,
                         const u16* __restrict__ Vt, const float* __restrict__ slopes,
                         u16* __restrict__ O) {
  const int bx = blockIdx.x;
  const int h = blockIdx.y;
  const int t = threadIdx.x, lane = t & 63, w = t >> 6;
  const int g = lane >> 4, l16 = lane & 15;
  const float slope = slopes[h];

  __shared__ u16 Ps[4][16][72];  // per-wave P tile, padded stride

#pragma unroll 1
  for (int pi = 0; pi < 2; ++pi) {
    const int qb = pi == 0 ? bx : 31 - bx;
    const int q0 = qb * 64 + w * 16;

    bf16x8 qf[2];
#pragma unroll
    for (int kk = 0; kk < 2; ++kk)
      qf[kk] = *(const bf16x8*)&Q[(size_t)(q0 + l16) * 1024 + h * 64 + kk * 32 + g * 8];

    f32x4 o_acc[4] = {};
    float m_run[4], l_run[4];
#pragma unroll
    for (int r = 0; r < 4; ++r) { m_run[r] = -1e30f; l_run[r] = 0.f; }

    for (int j = 0; j <= qb; ++j) {
      const int kv0 = j * 64;
      // ---- S = Q K^T (16 q-rows x 64 keys per wave) ----
      f32x4 s[4];
#pragma unroll
      for (int n = 0; n < 4; ++n) {
        bf16x8 kf0 = *(const bf16x8*)&Kb[(size_t)(kv0 + n * 16 + l16) * 1024 + h * 64 + g * 8];
        bf16x8 kf1 = *(const bf16x8*)&Kb[(size_t)(kv0 + n * 16 + l16) * 1024 + h * 64 + 32 + g * 8];
        f32x4 z = {};
        s[n] = __builtin_amdgcn_mfma_f32_16x16x32_bf16(qf[0], kf0, z, 0, 0, 0);
        s[n] = __builtin_amdgcn_mfma_f32_16x16x32_bf16(qf[1], kf1, s[n], 0, 0, 0);
      }
      // ---- scale + ALiBi + causal mask ----
      float sv[4][4];
      float mtile[4] = { -1e30f, -1e30f, -1e30f, -1e30f };
#pragma unroll
      for (int n = 0; n < 4; ++n) {
        int kj = kv0 + n * 16 + l16;
#pragma unroll
        for (int r = 0; r < 4; ++r) {
          int qi = q0 + g * 4 + r;
          float val = s[n][r] * 0.125f - slope * (float)(kj - qi);
          val = (kj <= qi) ? val : -1e30f;
          sv[n][r] = val;
          mtile[r] = fmaxf(mtile[r], val);
        }
      }
      // ---- online softmax: row stats across the 16-lane group ----
#pragma unroll
      for (int r = 0; r < 4; ++r) {
        float v = mtile[r];
        v = fmaxf(v, __shfl_xor(v, 1));
        v = fmaxf(v, __shfl_xor(v, 2));
        v = fmaxf(v, __shfl_xor(v, 4));
        v = fmaxf(v, __shfl_xor(v, 8));
        mtile[r] = v;
      }
      float sc[4];
#pragma unroll
      for (int r = 0; r < 4; ++r) {
        float mnew = fmaxf(m_run[r], mtile[r]);
        sc[r] = __expf(m_run[r] - mnew);
        m_run[r] = mnew;
      }
      float tsum[4] = { 0.f, 0.f, 0.f, 0.f };
#pragma unroll
      for (int n = 0; n < 4; ++n)
#pragma unroll
        for (int r = 0; r < 4; ++r) {
          float p = __expf(sv[n][r] - m_run[r]);
          sv[n][r] = p;
          tsum[r] += p;
        }
#pragma unroll
      for (int r = 0; r < 4; ++r) {
        float v = tsum[r];
        v += __shfl_xor(v, 1);
        v += __shfl_xor(v, 2);
        v += __shfl_xor(v, 4);
        v += __shfl_xor(v, 8);
        l_run[r] = l_run[r] * sc[r] + v;
      }
#pragma unroll
      for (int d = 0; d < 4; ++d)
#pragma unroll
        for (int r = 0; r < 4; ++r) o_acc[d][r] *= sc[r];
      // ---- P -> LDS (layout fix for MFMA A-fragment), then O += P Vt^T ----
#pragma unroll
      for (int n = 0; n < 4; ++n)
#pragma unroll
        for (int r = 0; r < 4; ++r)
          Ps[w][g * 4 + r][n * 16 + l16] = f2bf(sv[n][r]);
      bf16x8 pf[2];
#pragma unroll
      for (int kk = 0; kk < 2; ++kk)
        pf[kk] = *(const bf16x8*)&Ps[w][l16][kk * 32 + g * 8];
#pragma unroll
      for (int d = 0; d < 4; ++d) {
#pragma unroll
        for (int kk = 0; kk < 2; ++kk) {
          bf16x8 vv = *(const bf16x8*)&Vt[((size_t)h * 64 + d * 16 + l16) * 2048 +
                                          kv0 + kk * 32 + g * 8];
          o_acc[d] = __builtin_amdgcn_mfma_f32_16x16x32_bf16(pf[kk], vv, o_acc[d], 0, 0, 0);
        }
      }
    }
    // ---- normalize + store ----
#pragma unroll
    for (int d = 0; d < 4; ++d)
#pragma unroll
      for (int r = 0; r < 4; ++r) {
        int row = q0 + g * 4 + r;
        O[(size_t)row * 1024 + h * 64 + d * 16 + l16] = f2bf(o_acc[d][r] / l_run[r]);
      }
  }
}

// ---------------- launcher ----------------
extern "C" void kernel_launch(void* const* d_in, const int* in_sizes, int n_in,
                              void* d_out, int out_size, void* d_ws, size_t ws_size,
                              hipStream_t stream) {
  const float* x = (const float*)d_in[0];
  const float* slopes = (const float*)d_in[1];
  const float* wq = (const float*)d_in[2];
  const float* wk = (const float*)d_in[3];
  const float* wv = (const float*)d_in[4];
  const float* wo = (const float*)d_in[5];
  const float* ff1w = (const float*)d_in[6];
  const float* ff1b = (const float*)d_in[7];
  const float* ff2w = (const float*)d_in[8];
  const float* ff2b = (const float*)d_in[9];
  const float* ln1g = (const float*)d_in[10];
  const float* ln1b = (const float*)d_in[11];
  const float* ln2g = (const float*)d_in[12];
  const float* ln2b = (const float*)d_in[13];
  float* out = (float*)d_out;

  if (ws_size < (size_t)(56u << 20)) return;  // need 56MB scratch

  char* ws = (char*)d_ws;
  u16* hbuf = (u16*)(ws + 0);             // 4MB: h (LN1 out), later reused as attn output
  u16* Qb = (u16*)(ws + (4u << 20));      // 4MB
  u16* Kbf = (u16*)(ws + (8u << 20));     // 4MB
  u16* Vbf = (u16*)(ws + (12u << 20));    // 4MB
  u16* Vtb = (u16*)(ws + (16u << 20));    // 4MB: transposed V [16][64][2048]
  u16* ffact = Qb;                        // 16MB span 4-20MB (Q/K/V/Vt dead after attention)
  float* x2 = (float*)(ws + (20u << 20)); // 8MB
  u16* h2 = (u16*)(ws + (28u << 20));     // 4MB
  u16* wqb = (u16*)(ws + (32u << 20));
  u16* wkb = (u16*)(ws + (34u << 20));
  u16* wvb = (u16*)(ws + (36u << 20));
  u16* wob = (u16*)(ws + (38u << 20));
  u16* ff1wb = (u16*)(ws + (40u << 20));  // 8MB
  u16* ff2wb = (u16*)(ws + (48u << 20));  // 8MB
  u16* attnO = hbuf;

  auto cvt = [&](const float* src, u16* dst, int n) {
    int n4 = n >> 2;
    cvt_f32_bf16<<<(n4 + 255) / 256, 256, 0, stream>>>(src, dst, n4);
  };
  cvt(wq, wqb, 1 << 20);
  cvt(wk, wkb, 1 << 20);
  cvt(wv, wvb, 1 << 20);
  cvt(wo, wob, 1 << 20);
  cvt(ff1w, ff1wb, 1 << 22);
  cvt(ff2w, ff2wb, 1 << 22);

  ln_rows<<<2048, 256, 0, stream>>>(x, ln1g, ln1b, hbuf);
  gemm_qkv<<<dim3(24, 16), 256, 0, stream>>>(hbuf, wqb, wkb, wvb, Qb, Kbf, Vbf);
  transpose_v<<<dim3(32, 16), 256, 0, stream>>>(Vbf, Vtb);
  attn_fwd<<<dim3(16, 16), 256, 0, stream>>>(Qb, Kbf, Vtb, slopes, attnO);
  // x2 = x + attnO @ wo^T
  gemm_bt<64, 128, 1, 4, 3><<<dim3(8, 32), 256, 0, stream>>>(
      attnO, wob, x2, nullptr, x, 2048, 1024, 1024);
  ln_rows<<<2048, 256, 0, stream>>>(x2, ln2g, ln2b, h2);
  // ffact = gelu(h2 @ ff1^T + b1)
  gemm_bt<128, 128, 2, 2, 1><<<dim3(32, 16), 256, 0, stream>>>(
      h2, ff1wb, ffact, ff1b, nullptr, 2048, 4096, 1024);
  // out = x2 + ffact @ ff2^T + b2
  gemm_bt<64, 128, 1, 4, 2><<<dim3(8, 32), 256, 0, stream>>>(
      ffact, ff2wb, out, ff2b, x2, 2048, 1024, 4096);
}